// Round 1
// baseline (1252.021 us; speedup 1.0000x reference)
//
#include <hip/hip_runtime.h>
#include <math.h>

// GlobalSphereAttention: LN -> QKV -> per-head dots * scale * (1+sph)
//   -> cross-head mean/std(ddof=1) normalize -> softmax(j) -> PV -> out proj.
// B=2, N=2048, DIM=512, HEADS=8, DHEAD=64. All fp32 this round.

constexpr int kDim = 512;
constexpr int kHeads = 8;
constexpr int kDh = 64;
constexpr int kN = 2048;
constexpr float kEps = 1e-5f;
constexpr float kScale = 0.125f; // 64^-0.5

// ws layout (float offsets)
constexpr size_t WS_Q  = 0;          // [B][H][N][Dh] = 2,097,152
constexpr size_t WS_K  = 2097152;
constexpr size_t WS_V  = 4194304;
constexpr size_t WS_AO = 6291456;    // [B][N][512]
constexpr size_t WS_MU = 8388608;    // [4096]
constexpr size_t WS_RS = 8392704;    // [4096]

// ---------------- K1: LayerNorm row stats ----------------
__global__ __launch_bounds__(256) void k_ln_stats(const float* __restrict__ x,
                                                  float* __restrict__ mu,
                                                  float* __restrict__ rs) {
  int row = blockIdx.x * 4 + (threadIdx.x >> 6);
  int lane = threadIdx.x & 63;
  const float4* xr = (const float4*)(x + (size_t)row * kDim + lane * 8);
  float4 a = xr[0], b = xr[1];
  float s = a.x + a.y + a.z + a.w + b.x + b.y + b.z + b.w;
  float q = a.x*a.x + a.y*a.y + a.z*a.z + a.w*a.w
          + b.x*b.x + b.y*b.y + b.z*b.z + b.w*b.w;
#pragma unroll
  for (int off = 32; off > 0; off >>= 1) {
    s += __shfl_down(s, off);
    q += __shfl_down(q, off);
  }
  if (lane == 0) {
    float m = s * (1.0f / kDim);
    float v = q * (1.0f / kDim) - m * m;
    mu[row] = m;
    rs[row] = 1.0f / sqrtf(v + kEps);
  }
}

// ---------------- K2: fused-LN QKV GEMM [4096,512]x[512,1536] ----------------
__global__ __launch_bounds__(256) void k_gemm_qkv(const float* __restrict__ x,
    const float* __restrict__ mu, const float* __restrict__ rs,
    const float* __restrict__ g, const float* __restrict__ bta,
    const float* __restrict__ w, float* __restrict__ qkv) {
  __shared__ float As[16][68];  // A^T tile (k-major)
  __shared__ float Bs[16][68];
  const int t = threadIdx.x;
  const int colBase = blockIdx.x * 64;
  const int rowBase = blockIdx.y * 64;
  const int ti = t >> 4, tj = t & 15;
  const int ar = t >> 2, ak = (t & 3) * 4;
  const int bk = t >> 4, bc = (t & 15) * 4;
  const int arow = rowBase + ar;
  const float amu = mu[arow], ars = rs[arow];
  float acc[4][4] = {};
  for (int kt = 0; kt < kDim; kt += 16) {
    float4 av = *(const float4*)(x + (size_t)arow * kDim + kt + ak);
    float4 gv = *(const float4*)(g + kt + ak);
    float4 bv = *(const float4*)(bta + kt + ak);
    float4 wv = *(const float4*)(w + (size_t)(kt + bk) * 1536 + colBase + bc);
    As[ak + 0][ar] = (av.x - amu) * ars * gv.x + bv.x;
    As[ak + 1][ar] = (av.y - amu) * ars * gv.y + bv.y;
    As[ak + 2][ar] = (av.z - amu) * ars * gv.z + bv.z;
    As[ak + 3][ar] = (av.w - amu) * ars * gv.w + bv.w;
    *(float4*)&Bs[bk][bc] = wv;
    __syncthreads();
#pragma unroll
    for (int kk = 0; kk < 16; ++kk) {
      float4 a4 = *(const float4*)&As[kk][ti * 4];
      float4 b4 = *(const float4*)&Bs[kk][tj * 4];
      float aa[4] = {a4.x, a4.y, a4.z, a4.w};
      float bb2[4] = {b4.x, b4.y, b4.z, b4.w};
#pragma unroll
      for (int r = 0; r < 4; ++r)
#pragma unroll
        for (int c = 0; c < 4; ++c)
          acc[r][c] += aa[r] * bb2[c];
    }
    __syncthreads();
  }
  // scatter to q/k/v in [b][h][n][d] layout
  const int col0 = colBase + tj * 4;
  const int which = col0 >> 9;
  const int cc = col0 & 511;
  const int h = cc >> 6, d = cc & 63;
#pragma unroll
  for (int r = 0; r < 4; ++r) {
    int row = rowBase + ti * 4 + r;
    int bI = row >> 11, n = row & 2047;
    float4 vv = make_float4(acc[r][0], acc[r][1], acc[r][2], acc[r][3]);
    *(float4*)(qkv + (size_t)which * 2097152 +
               ((size_t)(bI * kHeads + h) * kN + n) * kDh + d) = vv;
  }
}

// ---------------- K3: fused sphere attention ----------------
// grid = B * (N/16) = 256 blocks, 256 threads.
// Per block: 16 query rows, all 8 heads. Loop j in tiles of 32.
__global__ __launch_bounds__(256) void k_attn(const float* __restrict__ qb,
    const float* __restrict__ kb, const float* __restrict__ vb,
    const float* __restrict__ sph, float* __restrict__ ao) {
  constexpr int QSTR = 520, KSTR = 520, SSJ = 33;
  __shared__ float Qs[16 * QSTR];    // swizzled: quad ^= (i>>2)&3
  __shared__ float KVs[32 * KSTR];   // swizzled: quad ^= (j>>2)&7 (K then V)
  __shared__ float Ss[128 * SSJ];    // [h*16+i][j] scores -> P
  __shared__ float Ms[128], Ls[128], Fs[128];
  const int t = threadIdx.x;
  const int bI = blockIdx.x >> 7;
  const int i0 = (blockIdx.x & 127) << 4;

  // load Q tile (16 rows x 512) with swizzle
  for (int e = t * 4; e < 16 * 512; e += 1024) {
    int i = e >> 9, c = e & 511;
    int h = c >> 6, d = c & 63;
    float4 v = *(const float4*)(qb + ((size_t)(bI * kHeads + h) * kN + i0 + i) * kDh + d);
    int qd = (c >> 2) ^ ((i >> 2) & 3);
    *(float4*)&Qs[i * QSTR + qd * 4] = v;
  }
  if (t < 128) { Ms[t] = -INFINITY; Ls[t] = 0.0f; }

  const int ha = t >> 5, i4 = (t >> 3) & 3, j4 = t & 7;  // phase-a ids
  const int ig = t & 3, cg = t >> 2;                     // phase-c ids
  const int c0 = cg * 8, hc = cg >> 3;
  float o[4][8];
#pragma unroll
  for (int r = 0; r < 4; ++r)
#pragma unroll
    for (int c = 0; c < 8; ++c) o[r][c] = 0.0f;

  for (int j0 = 0; j0 < kN; j0 += 32) {
    // ---- stage K tile (32 x 512) ----
    for (int e = t * 4; e < 32 * 512; e += 1024) {
      int j = e >> 9, c = e & 511;
      int h = c >> 6, d = c & 63;
      float4 v = *(const float4*)(kb + ((size_t)(bI * kHeads + h) * kN + j0 + j) * kDh + d);
      int qd = (c >> 2) ^ ((j >> 2) & 7);
      *(float4*)&KVs[j * KSTR + qd * 4] = v;
    }
    __syncthreads();
    // ---- phase a: dots, all heads; thread = (h, 4i x 4j tile) ----
    {
      float s[4][4] = {};
#pragma unroll 4
      for (int dq = 0; dq < 16; ++dq) {
        int cq = ha * 16 + dq;
        float4 qv[4], kv[4];
#pragma unroll
        for (int r = 0; r < 4; ++r)
          qv[r] = *(const float4*)&Qs[(i4 * 4 + r) * QSTR + (cq ^ i4) * 4];
#pragma unroll
        for (int c = 0; c < 4; ++c)
          kv[c] = *(const float4*)&KVs[(j4 * 4 + c) * KSTR + (cq ^ j4) * 4];
#pragma unroll
        for (int r = 0; r < 4; ++r)
#pragma unroll
          for (int c = 0; c < 4; ++c)
            s[r][c] += qv[r].x * kv[c].x + qv[r].y * kv[c].y +
                       qv[r].z * kv[c].z + qv[r].w * kv[c].w;
      }
#pragma unroll
      for (int r = 0; r < 4; ++r)
#pragma unroll
        for (int c = 0; c < 4; ++c)
          Ss[(ha * 16 + i4 * 4 + r) * SSJ + j4 * 4 + c] = s[r][c];
    }
    __syncthreads();
    // ---- stage V tile (overwrites KVs; K reads are done) ----
    for (int e = t * 4; e < 32 * 512; e += 1024) {
      int j = e >> 9, c = e & 511;
      int h = c >> 6, d = c & 63;
      float4 v = *(const float4*)(vb + ((size_t)(bI * kHeads + h) * kN + j0 + j) * kDh + d);
      int qd = (c >> 2) ^ ((j >> 2) & 7);
      *(float4*)&KVs[j * KSTR + qd * 4] = v;
    }
    // ---- phase b1: scale*(1+sph), cross-head mean/std normalize ----
#pragma unroll
    for (int pp = 0; pp < 2; ++pp) {
      int p = t * 2 + pp;
      int i = p >> 5, j = p & 31;
      float mult = kScale * (1.0f + sph[(size_t)(i0 + i) * kN + j0 + j]);
      float d8[8];
      float sum = 0.0f;
#pragma unroll
      for (int h = 0; h < 8; ++h) {
        d8[h] = Ss[(h * 16 + i) * SSJ + j] * mult;
        sum += d8[h];
      }
      float mean = sum * 0.125f;
      float var = 0.0f;
#pragma unroll
      for (int h = 0; h < 8; ++h) {
        float dd = d8[h] - mean;
        var += dd * dd;
      }
      float inv = 1.0f / sqrtf(var * (1.0f / 7.0f));
#pragma unroll
      for (int h = 0; h < 8; ++h)
        Ss[(h * 16 + i) * SSJ + j] = (d8[h] - mean) * inv;
    }
    __syncthreads();
    // ---- phase b2: online softmax per (h,i) row ----
    if (t < 128) {
      float* row = &Ss[t * SSJ];
      float mx = row[0];
      for (int j = 1; j < 32; ++j) mx = fmaxf(mx, row[j]);
      float Mo = Ms[t];
      float Mn = fmaxf(Mo, mx);
      float f = __expf(Mo - Mn);
      float sum = 0.0f;
      for (int j = 0; j < 32; ++j) {
        float p = __expf(row[j] - Mn);
        row[j] = p;
        sum += p;
      }
      Ms[t] = Mn;
      Ls[t] = Ls[t] * f + sum;
      Fs[t] = f;
    }
    __syncthreads();
    // ---- phase c: O = O*f + P @ V; thread = (4i x 8cols) ----
    {
      float fr[4];
#pragma unroll
      for (int r = 0; r < 4; ++r) fr[r] = Fs[hc * 16 + ig * 4 + r];
#pragma unroll
      for (int r = 0; r < 4; ++r)
#pragma unroll
        for (int c = 0; c < 8; ++c) o[r][c] *= fr[r];
#pragma unroll 4
      for (int j = 0; j < 32; ++j) {
        int sw = (j >> 2) & 7;
        float4 va = *(const float4*)&KVs[j * KSTR + ((cg * 2) ^ sw) * 4];
        float4 vb4 = *(const float4*)&KVs[j * KSTR + ((cg * 2 + 1) ^ sw) * 4];
#pragma unroll
        for (int r = 0; r < 4; ++r) {
          float p = Ss[(hc * 16 + ig * 4 + r) * SSJ + j];
          o[r][0] += p * va.x;  o[r][1] += p * va.y;
          o[r][2] += p * va.z;  o[r][3] += p * va.w;
          o[r][4] += p * vb4.x; o[r][5] += p * vb4.y;
          o[r][6] += p * vb4.z; o[r][7] += p * vb4.w;
        }
      }
    }
    __syncthreads();
  }
  // epilogue: O / L -> attn_out [b][n][h*64+d]
#pragma unroll
  for (int r = 0; r < 4; ++r) {
    float invL = 1.0f / Ls[hc * 16 + ig * 4 + r];
    int row = i0 + ig * 4 + r;
    float* dst = ao + ((size_t)bI * kN + row) * 512 + c0;
    float4 w0 = make_float4(o[r][0] * invL, o[r][1] * invL, o[r][2] * invL, o[r][3] * invL);
    float4 w1 = make_float4(o[r][4] * invL, o[r][5] * invL, o[r][6] * invL, o[r][7] * invL);
    ((float4*)dst)[0] = w0;
    ((float4*)dst)[1] = w1;
  }
}

// ---------------- K4: out projection [4096,512]x[512,512] + bias ----------------
__global__ __launch_bounds__(256) void k_gemm_out(const float* __restrict__ a,
    const float* __restrict__ w, const float* __restrict__ bias,
    float* __restrict__ out) {
  __shared__ float As[16][68];
  __shared__ float Bs[16][68];
  const int t = threadIdx.x;
  const int colBase = blockIdx.x * 64;
  const int rowBase = blockIdx.y * 64;
  const int ti = t >> 4, tj = t & 15;
  const int ar = t >> 2, ak = (t & 3) * 4;
  const int bk = t >> 4, bc = (t & 15) * 4;
  float acc[4][4] = {};
  for (int kt = 0; kt < 512; kt += 16) {
    float4 av = *(const float4*)(a + (size_t)(rowBase + ar) * 512 + kt + ak);
    float4 wv = *(const float4*)(w + (size_t)(kt + bk) * 512 + colBase + bc);
    As[ak + 0][ar] = av.x;
    As[ak + 1][ar] = av.y;
    As[ak + 2][ar] = av.z;
    As[ak + 3][ar] = av.w;
    *(float4*)&Bs[bk][bc] = wv;
    __syncthreads();
#pragma unroll
    for (int kk = 0; kk < 16; ++kk) {
      float4 a4 = *(const float4*)&As[kk][ti * 4];
      float4 b4 = *(const float4*)&Bs[kk][tj * 4];
      float aa[4] = {a4.x, a4.y, a4.z, a4.w};
      float bb2[4] = {b4.x, b4.y, b4.z, b4.w};
#pragma unroll
      for (int r = 0; r < 4; ++r)
#pragma unroll
        for (int c = 0; c < 4; ++c)
          acc[r][c] += aa[r] * bb2[c];
    }
    __syncthreads();
  }
  float4 bias4 = *(const float4*)(bias + colBase + tj * 4);
#pragma unroll
  for (int r = 0; r < 4; ++r) {
    int row = rowBase + ti * 4 + r;
    float4 vv = make_float4(acc[r][0] + bias4.x, acc[r][1] + bias4.y,
                            acc[r][2] + bias4.z, acc[r][3] + bias4.w);
    *(float4*)(out + (size_t)row * 512 + colBase + tj * 4) = vv;
  }
}

extern "C" void kernel_launch(void* const* d_in, const int* in_sizes, int n_in,
                              void* d_out, int out_size, void* d_ws, size_t ws_size,
                              hipStream_t stream) {
  (void)in_sizes; (void)n_in; (void)out_size; (void)ws_size;
  const float* x    = (const float*)d_in[0];
  const float* sph  = (const float*)d_in[1];
  const float* g    = (const float*)d_in[2];
  const float* bta  = (const float*)d_in[3];
  const float* wqkv = (const float*)d_in[4];
  const float* wout = (const float*)d_in[5];
  const float* bout = (const float*)d_in[6];
  float* out = (float*)d_out;
  float* ws = (float*)d_ws;

  k_ln_stats<<<dim3(1024), dim3(256), 0, stream>>>(x, ws + WS_MU, ws + WS_RS);
  k_gemm_qkv<<<dim3(24, 64), dim3(256), 0, stream>>>(x, ws + WS_MU, ws + WS_RS,
                                                     g, bta, wqkv, ws + WS_Q);
  k_attn<<<dim3(256), dim3(256), 0, stream>>>(ws + WS_Q, ws + WS_K, ws + WS_V,
                                              sph, ws + WS_AO);
  k_gemm_out<<<dim3(8, 64), dim3(256), 0, stream>>>(ws + WS_AO, wout, bout, out);
}

// Round 2
// 407.886 us; speedup vs baseline: 3.0695x; 3.0695x over previous
//
#include <hip/hip_runtime.h>
#include <math.h>

// GlobalSphereAttention: LN -> QKV -> per-head dots * scale * (1+sph)
//   -> cross-head mean/std(ddof=1) normalize -> softmax(j) -> PV -> out proj.
// B=2, N=2048, DIM=512, HEADS=8, DHEAD=64.
// Round 2: MFMA bf16 hi/lo split attention (wave=head), Q-tile 16.

typedef __attribute__((ext_vector_type(8))) short bf16x8;
typedef __attribute__((ext_vector_type(4))) float f32x4;

constexpr int kDim = 512;
constexpr int kN = 2048;
constexpr float kEps = 1e-5f;
constexpr float kScale = 0.125f; // 64^-0.5

// ws layout (byte offsets); planes are ushort (bf16 bits)
constexpr size_t OFF_QHI = 0;
constexpr size_t OFF_QLO = 4u << 20;
constexpr size_t OFF_KHI = 8u << 20;
constexpr size_t OFF_KLO = 12u << 20;
constexpr size_t OFF_VTHI = 16u << 20;  // transposed [bh][d][n]
constexpr size_t OFF_VTLO = 20u << 20;
constexpr size_t OFF_AO = 24u << 20;    // f32 [b][n][512]
constexpr size_t OFF_MU = 32u << 20;
constexpr size_t OFF_RS = (32u << 20) + (16u << 10);

__device__ __forceinline__ unsigned short bf16_rne(float f) {
  unsigned int u = __float_as_uint(f);
  u += 0x7fffu + ((u >> 16) & 1u);
  return (unsigned short)(u >> 16);
}
__device__ __forceinline__ float bf16f(unsigned short h) {
  return __uint_as_float(((unsigned int)h) << 16);
}
__device__ __forceinline__ f32x4 mfma16(bf16x8 a, bf16x8 b, f32x4 c) {
  return __builtin_amdgcn_mfma_f32_16x16x32_bf16(a, b, c, 0, 0, 0);
}

// ---------------- K1: LayerNorm row stats ----------------
__global__ __launch_bounds__(256) void k_ln_stats(const float* __restrict__ x,
                                                  float* __restrict__ mu,
                                                  float* __restrict__ rs) {
  int row = blockIdx.x * 4 + (threadIdx.x >> 6);
  int lane = threadIdx.x & 63;
  const float4* xr = (const float4*)(x + (size_t)row * kDim + lane * 8);
  float4 a = xr[0], b = xr[1];
  float s = a.x + a.y + a.z + a.w + b.x + b.y + b.z + b.w;
  float q = a.x*a.x + a.y*a.y + a.z*a.z + a.w*a.w
          + b.x*b.x + b.y*b.y + b.z*b.z + b.w*b.w;
#pragma unroll
  for (int off = 32; off > 0; off >>= 1) {
    s += __shfl_down(s, off);
    q += __shfl_down(q, off);
  }
  if (lane == 0) {
    float m = s * (1.0f / kDim);
    float v = q * (1.0f / kDim) - m * m;
    mu[row] = m;
    rs[row] = 1.0f / sqrtf(v + kEps);
  }
}

// ---------------- K2: fused-LN QKV GEMM, epilogue -> bf16 hi/lo planes ------
__global__ __launch_bounds__(256) void k_gemm_qkv(const float* __restrict__ x,
    const float* __restrict__ mu, const float* __restrict__ rs,
    const float* __restrict__ g, const float* __restrict__ bta,
    const float* __restrict__ w,
    unsigned short* __restrict__ qhi, unsigned short* __restrict__ qlo,
    unsigned short* __restrict__ khi, unsigned short* __restrict__ klo,
    unsigned short* __restrict__ vthi, unsigned short* __restrict__ vtlo) {
  __shared__ float As[16][68];  // A^T tile (k-major)
  __shared__ float Bs[16][68];
  const int t = threadIdx.x;
  const int colBase = blockIdx.x * 64;
  const int rowBase = blockIdx.y * 64;
  const int ti = t >> 4, tj = t & 15;
  const int ar = t >> 2, ak = (t & 3) * 4;
  const int bk = t >> 4, bc = (t & 15) * 4;
  const int arow = rowBase + ar;
  const float amu = mu[arow], ars = rs[arow];
  float acc[4][4] = {};
  for (int kt = 0; kt < kDim; kt += 16) {
    float4 av = *(const float4*)(x + (size_t)arow * kDim + kt + ak);
    float4 gv = *(const float4*)(g + kt + ak);
    float4 bv = *(const float4*)(bta + kt + ak);
    float4 wv = *(const float4*)(w + (size_t)(kt + bk) * 1536 + colBase + bc);
    As[ak + 0][ar] = (av.x - amu) * ars * gv.x + bv.x;
    As[ak + 1][ar] = (av.y - amu) * ars * gv.y + bv.y;
    As[ak + 2][ar] = (av.z - amu) * ars * gv.z + bv.z;
    As[ak + 3][ar] = (av.w - amu) * ars * gv.w + bv.w;
    *(float4*)&Bs[bk][bc] = wv;
    __syncthreads();
#pragma unroll
    for (int kk = 0; kk < 16; ++kk) {
      float4 a4 = *(const float4*)&As[kk][ti * 4];
      float4 b4 = *(const float4*)&Bs[kk][tj * 4];
      float aa[4] = {a4.x, a4.y, a4.z, a4.w};
      float bb2[4] = {b4.x, b4.y, b4.z, b4.w};
#pragma unroll
      for (int r = 0; r < 4; ++r)
#pragma unroll
        for (int c = 0; c < 4; ++c)
          acc[r][c] += aa[r] * bb2[c];
    }
    __syncthreads();
  }
  const int col0 = colBase + tj * 4;
  const int which = col0 >> 9;
  const int cc = col0 & 511;
  const int h = cc >> 6, d = cc & 63;
  if (which < 2) {
    unsigned short* ph = (which == 0) ? qhi : khi;
    unsigned short* pl = (which == 0) ? qlo : klo;
#pragma unroll
    for (int r = 0; r < 4; ++r) {
      int row = rowBase + ti * 4 + r;
      int bI = row >> 11, n = row & 2047;
      size_t base = ((size_t)(bI * 8 + h) * kN + n) * 64 + d;
      unsigned short hv[4], lv[4];
#pragma unroll
      for (int c = 0; c < 4; ++c) {
        hv[c] = bf16_rne(acc[r][c]);
        lv[c] = bf16_rne(acc[r][c] - bf16f(hv[c]));
      }
      *(ushort4*)(ph + base) = make_ushort4(hv[0], hv[1], hv[2], hv[3]);
      *(ushort4*)(pl + base) = make_ushort4(lv[0], lv[1], lv[2], lv[3]);
    }
  } else {
    int row0 = rowBase + ti * 4;
    int bI = row0 >> 11, n0 = row0 & 2047;
#pragma unroll
    for (int c = 0; c < 4; ++c) {
      size_t base = ((size_t)(bI * 8 + h) * 64 + d + c) * kN + n0;
      unsigned short hv[4], lv[4];
#pragma unroll
      for (int r = 0; r < 4; ++r) {
        hv[r] = bf16_rne(acc[r][c]);
        lv[r] = bf16_rne(acc[r][c] - bf16f(hv[r]));
      }
      *(ushort4*)(vthi + base) = make_ushort4(hv[0], hv[1], hv[2], hv[3]);
      *(ushort4*)(vtlo + base) = make_ushort4(lv[0], lv[1], lv[2], lv[3]);
    }
  }
}

// ---------------- K3: fused sphere attention, MFMA hi/lo ----------------
// grid = B * (N/16) = 256 blocks x 512 threads. wave = head.
__global__ __launch_bounds__(512) void k_attn(
    const unsigned short* __restrict__ qhi, const unsigned short* __restrict__ qlo,
    const unsigned short* __restrict__ khi, const unsigned short* __restrict__ klo,
    const unsigned short* __restrict__ vthi, const unsigned short* __restrict__ vtlo,
    const float* __restrict__ sph, float* __restrict__ ao) {
  constexpr int STR = 68;          // dwords per score row (conflict-free)
  constexpr int STRH = 16 * STR;   // dwords per head
  __shared__ float Ss[8 * STRH];   // 34.8 KB, also holds packed P (u32)
  __shared__ float Fbuf[8][16];
  __shared__ float Lbuf[8][16];

  const int t = threadIdx.x;
  const int h = t >> 6;
  const int lane = t & 63;
  const int col = lane & 15;
  const int g = lane >> 4;
  const int bI = blockIdx.x >> 7;
  const int i0 = (blockIdx.x & 127) << 4;
  const size_t bh = (size_t)bI * 8 + h;

  // Q fragments (A-frag: row=lane&15, k=d=g*8+e), hi/lo, chunks d0=0,32
  const size_t qoff = (bh * kN + i0 + col) * 64 + g * 8;
  const bf16x8 qh0 = *(const bf16x8*)(qhi + qoff);
  const bf16x8 qh1 = *(const bf16x8*)(qhi + qoff + 32);
  const bf16x8 ql0 = *(const bf16x8*)(qlo + qoff);
  const bf16x8 ql1 = *(const bf16x8*)(qlo + qoff + 32);

  const unsigned short* kb_hi = khi + (bh * kN + col) * 64 + g * 8;
  const unsigned short* kb_lo = klo + (bh * kN + col) * 64 + g * 8;
  const unsigned short* vb_hi = vthi + (bh * 64 + col) * kN + g * 8;
  const unsigned short* vb_lo = vtlo + (bh * 64 + col) * kN + g * 8;

  // prologue: K frags for tile 0 (B-frag: col=j, k=d=g*8+e)
  bf16x8 kh[8], kl[8];
#pragma unroll
  for (int jf = 0; jf < 4; ++jf)
#pragma unroll
    for (int c = 0; c < 2; ++c) {
      kh[jf * 2 + c] = *(const bf16x8*)(kb_hi + (size_t)(jf * 16) * 64 + c * 32);
      kl[jf * 2 + c] = *(const bf16x8*)(kb_lo + (size_t)(jf * 16) * 64 + c * 32);
    }

  f32x4 oacc[4];
#pragma unroll
  for (int nf = 0; nf < 4; ++nf) oacc[nf] = (f32x4){0.f, 0.f, 0.f, 0.f};
  float mreg = -INFINITY, lreg = 0.f;

  const int si = col;   // softmax row
  const int sp = g;     // softmax j-part
  const float* srow = &Ss[h * STRH + si * STR + sp * 16];
  unsigned int* sb32 = (unsigned int*)Ss;
  const int swz = (si & 3) * 8;

  for (int j0 = 0; j0 < kN; j0 += 64) {
    // ---- QK^T: S = Qhi Khi + Qlo Khi + Qhi Klo ----
    f32x4 sacc[4];
#pragma unroll
    for (int jf = 0; jf < 4; ++jf) {
      f32x4 a = (f32x4){0.f, 0.f, 0.f, 0.f};
      a = mfma16(qh0, kh[jf * 2 + 0], a);
      a = mfma16(qh1, kh[jf * 2 + 1], a);
      a = mfma16(ql0, kh[jf * 2 + 0], a);
      a = mfma16(ql1, kh[jf * 2 + 1], a);
      a = mfma16(qh0, kl[jf * 2 + 0], a);
      a = mfma16(qh1, kl[jf * 2 + 1], a);
      sacc[jf] = a;
    }
    // ---- issue V loads early (land during norm/softmax) ----
    bf16x8 vh[8], vl[8];
#pragma unroll
    for (int nf = 0; nf < 4; ++nf)
#pragma unroll
      for (int c = 0; c < 2; ++c) {
        vh[nf * 2 + c] = *(const bf16x8*)(vb_hi + (size_t)(nf * 16) * kN + j0 + c * 32);
        vl[nf * 2 + c] = *(const bf16x8*)(vb_lo + (size_t)(nf * 16) * kN + j0 + c * 32);
      }
    // ---- S -> LDS (C/D: col=lane&15=j, row=g*4+r=i); conflict-free @STR=68 ----
#pragma unroll
    for (int jf = 0; jf < 4; ++jf)
#pragma unroll
      for (int r = 0; r < 4; ++r)
        Ss[h * STRH + (g * 4 + r) * STR + jf * 16 + col] = sacc[jf][r];
    __syncthreads();
    // ---- cross-head normalization (all 512 threads, 2 (i,j) pairs each) ----
    {
      const int jn = t & 63;
      const int ib = t >> 6;
#pragma unroll
      for (int half = 0; half < 2; ++half) {
        const int ii = ib + half * 8;
        float mult = kScale * (1.0f + sph[(size_t)(i0 + ii) * kN + j0 + jn]);
        float d8[8];
        float sum = 0.f;
#pragma unroll
        for (int hh = 0; hh < 8; ++hh) {
          d8[hh] = Ss[hh * STRH + ii * STR + jn] * mult;
          sum += d8[hh];
        }
        float mean = sum * 0.125f;
        float var = 0.f;
#pragma unroll
        for (int hh = 0; hh < 8; ++hh) {
          float dd = d8[hh] - mean;
          var += dd * dd;
        }
        float inv = rsqrtf(var * (1.0f / 7.0f));
#pragma unroll
        for (int hh = 0; hh < 8; ++hh)
          Ss[hh * STRH + ii * STR + jn] = (d8[hh] - mean) * inv;
      }
    }
    __syncthreads();
    // ---- online softmax (own head; lane: row si, j-part sp) ----
    {
      float vals[16];
      float4 dv;
      dv = *(const float4*)(srow + 0);  vals[0]=dv.x; vals[1]=dv.y; vals[2]=dv.z; vals[3]=dv.w;
      dv = *(const float4*)(srow + 4);  vals[4]=dv.x; vals[5]=dv.y; vals[6]=dv.z; vals[7]=dv.w;
      dv = *(const float4*)(srow + 8);  vals[8]=dv.x; vals[9]=dv.y; vals[10]=dv.z; vals[11]=dv.w;
      dv = *(const float4*)(srow + 12); vals[12]=dv.x; vals[13]=dv.y; vals[14]=dv.z; vals[15]=dv.w;
      float mx = vals[0];
#pragma unroll
      for (int q = 1; q < 16; ++q) mx = fmaxf(mx, vals[q]);
      mx = fmaxf(mx, __shfl_xor(mx, 16));
      mx = fmaxf(mx, __shfl_xor(mx, 32));
      float Mn = fmaxf(mreg, mx);
      float f = __expf(mreg - Mn);
      float s = 0.f;
      float pvv[16];
#pragma unroll
      for (int q = 0; q < 16; ++q) {
        pvv[q] = __expf(vals[q] - Mn);
        s += pvv[q];
      }
      s += __shfl_xor(s, 16);
      s += __shfl_xor(s, 32);
      lreg = lreg * f + s;
      mreg = Mn;
      if (g == 0) Fbuf[h][si] = f;
      // pack P as (hi | lo<<16), store with XOR-8(i&3) swizzle (in place)
#pragma unroll
      for (int qq = 0; qq < 4; ++qq) {
        unsigned int pk[4];
#pragma unroll
        for (int e = 0; e < 4; ++e) {
          float p = pvv[qq * 4 + e];
          unsigned short hi2 = bf16_rne(p);
          unsigned short lo2 = bf16_rne(p - bf16f(hi2));
          pk[e] = (unsigned int)hi2 | ((unsigned int)lo2 << 16);
        }
        *(uint4*)(sb32 + h * STRH + si * STR + ((sp * 16 + qq * 4) ^ swz)) =
            make_uint4(pk[0], pk[1], pk[2], pk[3]);
      }
    }
    // ---- PV (same wave only -> no barrier): A=P hi/lo, B=V hi/lo ----
    bf16x8 ph[2], pl[2];
#pragma unroll
    for (int c = 0; c < 2; ++c) {
      const int base = h * STRH + col * STR + (c * 32 + 8 * (g ^ (col & 3)));
      uint4 u0 = *(const uint4*)((const unsigned int*)Ss + base);
      uint4 u1 = *(const uint4*)((const unsigned int*)Ss + base + 4);
      unsigned int uu[8] = {u0.x, u0.y, u0.z, u0.w, u1.x, u1.y, u1.z, u1.w};
      bf16x8 h8, l8;
#pragma unroll
      for (int e = 0; e < 8; ++e) {
        h8[e] = (short)(uu[e] & 0xffffu);
        l8[e] = (short)(uu[e] >> 16);
      }
      ph[c] = h8;
      pl[c] = l8;
    }
    float fr[4];
#pragma unroll
    for (int r = 0; r < 4; ++r) fr[r] = Fbuf[h][g * 4 + r];
#pragma unroll
    for (int nf = 0; nf < 4; ++nf) {
      f32x4 a = oacc[nf];
#pragma unroll
      for (int r = 0; r < 4; ++r) a[r] *= fr[r];
      a = mfma16(ph[0], vh[nf * 2 + 0], a);
      a = mfma16(ph[1], vh[nf * 2 + 1], a);
      a = mfma16(pl[0], vh[nf * 2 + 0], a);
      a = mfma16(pl[1], vh[nf * 2 + 1], a);
      a = mfma16(ph[0], vl[nf * 2 + 0], a);
      a = mfma16(ph[1], vl[nf * 2 + 1], a);
      oacc[nf] = a;
    }
    // ---- prefetch next K tile ----
    if (j0 + 64 < kN) {
      const size_t joff = (size_t)(j0 + 64) * 64;
#pragma unroll
      for (int jf = 0; jf < 4; ++jf)
#pragma unroll
        for (int c = 0; c < 2; ++c) {
          kh[jf * 2 + c] = *(const bf16x8*)(kb_hi + joff + (size_t)(jf * 16) * 64 + c * 32);
          kl[jf * 2 + c] = *(const bf16x8*)(kb_lo + joff + (size_t)(jf * 16) * 64 + c * 32);
        }
    }
  }
  // ---- epilogue: O / L -> ao[b][n][h*64+d] ----
  if (g == 0) Lbuf[h][si] = lreg;
#pragma unroll
  for (int r = 0; r < 4; ++r) {
    float invl = 1.0f / Lbuf[h][g * 4 + r];
    float* dst = ao + ((size_t)bI * kN + i0 + g * 4 + r) * 512 + h * 64;
#pragma unroll
    for (int nf = 0; nf < 4; ++nf)
      dst[nf * 16 + col] = oacc[nf][r] * invl;
  }
}

// ---------------- K4: out projection [4096,512]x[512,512] + bias ----------------
__global__ __launch_bounds__(256) void k_gemm_out(const float* __restrict__ a,
    const float* __restrict__ w, const float* __restrict__ bias,
    float* __restrict__ out) {
  __shared__ float As[16][68];
  __shared__ float Bs[16][68];
  const int t = threadIdx.x;
  const int colBase = blockIdx.x * 64;
  const int rowBase = blockIdx.y * 64;
  const int ti = t >> 4, tj = t & 15;
  const int ar = t >> 2, ak = (t & 3) * 4;
  const int bk = t >> 4, bc = (t & 15) * 4;
  float acc[4][4] = {};
  for (int kt = 0; kt < 512; kt += 16) {
    float4 av = *(const float4*)(a + (size_t)(rowBase + ar) * 512 + kt + ak);
    float4 wv = *(const float4*)(w + (size_t)(kt + bk) * 512 + colBase + bc);
    As[ak + 0][ar] = av.x;
    As[ak + 1][ar] = av.y;
    As[ak + 2][ar] = av.z;
    As[ak + 3][ar] = av.w;
    *(float4*)&Bs[bk][bc] = wv;
    __syncthreads();
#pragma unroll
    for (int kk = 0; kk < 16; ++kk) {
      float4 a4 = *(const float4*)&As[kk][ti * 4];
      float4 b4 = *(const float4*)&Bs[kk][tj * 4];
      float aa[4] = {a4.x, a4.y, a4.z, a4.w};
      float bb2[4] = {b4.x, b4.y, b4.z, b4.w};
#pragma unroll
      for (int r = 0; r < 4; ++r)
#pragma unroll
        for (int c = 0; c < 4; ++c)
          acc[r][c] += aa[r] * bb2[c];
    }
    __syncthreads();
  }
  float4 bias4 = *(const float4*)(bias + colBase + tj * 4);
#pragma unroll
  for (int r = 0; r < 4; ++r) {
    int row = rowBase + ti * 4 + r;
    float4 vv = make_float4(acc[r][0] + bias4.x, acc[r][1] + bias4.y,
                            acc[r][2] + bias4.z, acc[r][3] + bias4.w);
    *(float4*)(out + (size_t)row * 512 + colBase + tj * 4) = vv;
  }
}

extern "C" void kernel_launch(void* const* d_in, const int* in_sizes, int n_in,
                              void* d_out, int out_size, void* d_ws, size_t ws_size,
                              hipStream_t stream) {
  (void)in_sizes; (void)n_in; (void)out_size; (void)ws_size;
  const float* x    = (const float*)d_in[0];
  const float* sph  = (const float*)d_in[1];
  const float* g    = (const float*)d_in[2];
  const float* bta  = (const float*)d_in[3];
  const float* wqkv = (const float*)d_in[4];
  const float* wout = (const float*)d_in[5];
  const float* bout = (const float*)d_in[6];
  float* out = (float*)d_out;
  char* ws = (char*)d_ws;

  unsigned short* qhi = (unsigned short*)(ws + OFF_QHI);
  unsigned short* qlo = (unsigned short*)(ws + OFF_QLO);
  unsigned short* khi = (unsigned short*)(ws + OFF_KHI);
  unsigned short* klo = (unsigned short*)(ws + OFF_KLO);
  unsigned short* vthi = (unsigned short*)(ws + OFF_VTHI);
  unsigned short* vtlo = (unsigned short*)(ws + OFF_VTLO);
  float* ao = (float*)(ws + OFF_AO);
  float* mu = (float*)(ws + OFF_MU);
  float* rs = (float*)(ws + OFF_RS);

  k_ln_stats<<<dim3(1024), dim3(256), 0, stream>>>(x, mu, rs);
  k_gemm_qkv<<<dim3(24, 64), dim3(256), 0, stream>>>(x, mu, rs, g, bta, wqkv,
                                                     qhi, qlo, khi, klo, vthi, vtlo);
  k_attn<<<dim3(256), dim3(512), 0, stream>>>(qhi, qlo, khi, klo, vthi, vtlo,
                                              sph, ao);
  k_gemm_out<<<dim3(8, 64), dim3(256), 0, stream>>>(ao, wout, bout, out);
}